// Round 5
// baseline (291.676 us; speedup 1.0000x reference)
//
#include <hip/hip_runtime.h>
#include <math.h>

#define NEG_SLOPE 0.2f
#define TILE 8192    // edges per block in the scatter pass

using half8 = __attribute__((ext_vector_type(8))) _Float16;
using f32x4 = __attribute__((ext_vector_type(4))) float;

__device__ __forceinline__ float leaky(float x) { return x > 0.f ? x : NEG_SLOPE * x; }

__device__ __forceinline__ float wsum64(float v) {
#pragma unroll
  for (int off = 32; off; off >>= 1) v += __shfl_xor(v, off);
  return v;
}

// fp32 -> fp16 (RNE) and back. GEMM1 uses f16 hi + f16 residual for A (f32
// input x); GEMM2's A (hbuf) is STORED f16 so hi = exact, residual = 0 and
// the lo-MFMAs are skipped entirely. W single f16: dropped residual term
// ~2.5e-4, an order below the f16 xph storage floor (0.0039).
__device__ __forceinline__ unsigned short f2h(float f) {
  union { _Float16 h; unsigned short u; } x;
  x.h = (_Float16)f;
  return x.u;
}
__device__ __forceinline__ float h2f(unsigned short u) {
  union { unsigned short u; _Float16 h; } x;
  x.u = u;
  return (float)x.h;
}

// 8-channel f16 gather-accumulate: fmaf(p, fpext(f16), acc) -> v_fma_mix_f32
__device__ __forceinline__ void acc8h(float* a, float p, uint4 rv) {
  union { uint4 v; _Float16 h[8]; } u;
  u.v = rv;
#pragma unroll
  for (int j = 0; j < 8; ++j) a[j] = fmaf(p, (float)u.h[j], a[j]);
}

// lane-t's p for head h (4 cross-lane pulls + select)
__device__ __forceinline__ float getp(float p0, float p1, float p2, float p3,
                                      int h, int t) {
  float b0 = __shfl(p0, t), b1 = __shfl(p1, t);
  float b2 = __shfl(p2, t), b3 = __shfl(p3, t);
  float lo = (h & 1) ? b1 : b0;
  float hi = (h & 1) ? b3 : b2;
  return (h & 2) ? hi : lo;
}

// ---------------- f16 MFMA GEMM + fused logits (device body) ----------------
// AHALF=false: A is f32, split into f16 hi + f16 residual (4 MFMAs/ct).
// AHALF=true:  A is f16 (exact), no residual (2 MFMAs/ct, no Al buffer).
#define PA 136  // Ah/Al row pitch (f16): +8 pad
#define PW 40   // Wh row pitch
template <bool AHALF>
__device__ void gemm_body(
    const void* __restrict__ Av, const unsigned short* __restrict__ Wt,
    const float* __restrict__ a_src, const float* __restrict__ a_dst,
    unsigned short* __restrict__ xph, float* __restrict__ als,
    float* __restrict__ ald, int nrows, int blk) {
  __shared__ unsigned short Ah[64 * PA];
  __shared__ unsigned short Al[AHALF ? 64 : 64 * PA];  // unused when AHALF
  __shared__ unsigned short Wh[128 * PW];
  int t = threadIdx.x;
  int row0 = blk * 64;

  if constexpr (!AHALF) {
    const float4* A4 = (const float4*)Av;
#pragma unroll
    for (int p = 0; p < 8; ++p) {
      int idx = t + p * 256;  // 2048 float4 = 64 rows x 32
      int row = idx >> 5, k4 = idx & 31;
      int gr = row0 + row;
      float4 v = make_float4(0.f, 0.f, 0.f, 0.f);
      if (gr < nrows) v = A4[(size_t)gr * 32 + k4];
      ushort4 hi, lo;
      hi.x = f2h(v.x); lo.x = f2h(v.x - h2f(hi.x));
      hi.y = f2h(v.y); lo.y = f2h(v.y - h2f(hi.y));
      hi.z = f2h(v.z); lo.z = f2h(v.z - h2f(hi.z));
      hi.w = f2h(v.w); lo.w = f2h(v.w - h2f(hi.w));
      *(ushort4*)&Ah[row * PA + k4 * 4] = hi;
      *(ushort4*)&Al[row * PA + k4 * 4] = lo;
    }
  } else {
    const uint4* A4 = (const uint4*)Av;  // 8 halves per uint4; 16 per row
#pragma unroll
    for (int p = 0; p < 4; ++p) {
      int idx = t + p * 256;  // 1024 uint4 = 64 rows x 16
      int row = idx >> 4, k8 = idx & 15;
      int gr = row0 + row;
      uint4 v = make_uint4(0u, 0u, 0u, 0u);
      if (gr < nrows) v = A4[(size_t)gr * 16 + k8];
      *(uint4*)&Ah[row * PA + k8 * 8] = v;
    }
  }

  int lane = t & 63, wv = t >> 6;
  int wr = wv >> 1, wc = wv & 1;
  int ml = lane & 15, q = lane >> 4;
  f32x4 acc[2][4] = {};

  for (int kb = 0; kb < 4; ++kb) {
    __syncthreads();
    int k0 = kb * 32;
#pragma unroll
    for (int p = 0; p < 8; ++p) {
      int idx = t + p * 256;  // 2048 u32 = 128 n x 16 k-pairs
      int n = idx >> 4, kp = idx & 15;
      *(unsigned*)&Wh[n * PW + kp * 2] =
          *(const unsigned*)(Wt + (size_t)n * 128 + k0 + kp * 2);
    }
    __syncthreads();
    int kf = k0 + q * 8;
    half8 a_h0 = *(const half8*)&Ah[(wr * 32 + ml) * PA + kf];
    half8 a_h1 = *(const half8*)&Ah[(wr * 32 + 16 + ml) * PA + kf];
    half8 a_l0, a_l1;
    if constexpr (!AHALF) {
      a_l0 = *(const half8*)&Al[(wr * 32 + ml) * PA + kf];
      a_l1 = *(const half8*)&Al[(wr * 32 + 16 + ml) * PA + kf];
    }
#pragma unroll
    for (int ct = 0; ct < 4; ++ct) {
      int nb = (wc * 64 + ct * 16 + ml) * PW + q * 8;
      half8 b = *(const half8*)&Wh[nb];
      acc[0][ct] = __builtin_amdgcn_mfma_f32_16x16x32_f16(a_h0, b, acc[0][ct], 0, 0, 0);
      if constexpr (!AHALF)
        acc[0][ct] = __builtin_amdgcn_mfma_f32_16x16x32_f16(a_l0, b, acc[0][ct], 0, 0, 0);
      acc[1][ct] = __builtin_amdgcn_mfma_f32_16x16x32_f16(a_h1, b, acc[1][ct], 0, 0, 0);
      if constexpr (!AHALF)
        acc[1][ct] = __builtin_amdgcn_mfma_f32_16x16x32_f16(a_l1, b, acc[1][ct], 0, 0, 0);
    }
  }

  float asr[4], adr[4];
#pragma unroll
  for (int ct = 0; ct < 4; ++ct) {
    int col = (wc * 2 + (ct >> 1)) * 32 + (ct & 1) * 16 + ml;
    asr[ct] = a_src[col];
    adr[ct] = a_dst[col];
  }

#pragma unroll
  for (int rt = 0; rt < 2; ++rt) {
#pragma unroll
    for (int r = 0; r < 4; ++r) {
      int gr = row0 + wr * 32 + rt * 16 + q * 4 + r;
      bool valid = gr < nrows;
      if (valid) {
#pragma unroll
        for (int ct = 0; ct < 4; ++ct) {
          int gc = wc * 64 + ct * 16 + ml;
          xph[(size_t)gr * 128 + gc] = f2h(acc[rt][ct][r]);
        }
      }
      float p0 = acc[rt][0][r] * asr[0] + acc[rt][1][r] * asr[1];
      float p1 = acc[rt][2][r] * asr[2] + acc[rt][3][r] * asr[3];
      float d0 = acc[rt][0][r] * adr[0] + acc[rt][1][r] * adr[1];
      float d1 = acc[rt][2][r] * adr[2] + acc[rt][3][r] * adr[3];
#pragma unroll
      for (int off = 1; off <= 8; off <<= 1) {
        p0 += __shfl_xor(p0, off); p1 += __shfl_xor(p1, off);
        d0 += __shfl_xor(d0, off); d1 += __shfl_xor(d1, off);
      }
      if (ml == 0 && valid) {
        als[(size_t)gr * 4 + wc * 2] = p0;
        als[(size_t)gr * 4 + wc * 2 + 1] = p1;
        ald[(size_t)gr * 4 + wc * 2] = d0;
        ald[(size_t)gr * 4 + wc * 2 + 1] = d1;
      }
    }
  }
}

// ---------------- zero deg+cur (one contiguous region) ----------------
__global__ __launch_bounds__(256) void k_zero(int* __restrict__ p, int n) {
  int i = blockIdx.x * 256 + threadIdx.x;
  if (i < n) p[i] = 0;
}

// ---------------- per-node degree hist (global atomics) + W f16 convert ----------------
// Uniform dst over 50k nodes -> negligible same-address atomic contention.
__global__ __launch_bounds__(256) void k_hist_w(
    const int* __restrict__ dst, int* __restrict__ deg, int E, int nebl,
    const float* __restrict__ W0, const float* __restrict__ W1,
    unsigned short* __restrict__ Wt0, unsigned short* __restrict__ Wt1) {
  if (blockIdx.x < 128) {
    int i = blockIdx.x * 256 + threadIdx.x;  // 32768 total
    int j = i & 16383;
    int k = j >> 7, n = j & 127;
    const float* W = (i < 16384) ? W0 : W1;
    unsigned short hv = f2h(W[j]);
    if (i < 16384) Wt0[n * 128 + k] = hv;
    else Wt1[n * 128 + k] = hv;
    return;
  }
  int b = blockIdx.x - 128;
  for (int i = b * 256 + threadIdx.x; i < E; i += nebl * 256)
    atomicAdd(&deg[dst[i]], 1);
}

// ---------------- per-256-node block sums of deg ----------------
__global__ __launch_bounds__(256) void k_bsum(const int* __restrict__ deg,
                                              int* __restrict__ bsum, int N) {
  __shared__ int red[256];
  int b = blockIdx.x, t = threadIdx.x;
  int n = b * 256 + t;
  red[t] = (n < N) ? deg[n] : 0;
  __syncthreads();
  for (int off = 128; off; off >>= 1) {
    if (t < off) red[t] += red[t + off];
    __syncthreads();
  }
  if (t == 0) bsum[b] = red[0];
}

// ---------------- rstart = exclusive scan of deg (redundant block-sum scan) ----------------
// Each block redundantly scans the <=256 block sums, then locally scans its
// own 256 degs. nbs must be <= 256 (N=50000 -> 196).
__global__ __launch_bounds__(256) void k_rstart(
    const int* __restrict__ deg, const int* __restrict__ bsum,
    int* __restrict__ rstart, int N, int nbs) {
  __shared__ int sb[256];
  __shared__ int sd[256];
  int b = blockIdx.x, t = threadIdx.x;
  int bv = (t < nbs) ? bsum[t] : 0;
  sb[t] = bv;
  __syncthreads();
  for (int off = 1; off < 256; off <<= 1) {
    int add = (t >= off) ? sb[t - off] : 0;
    __syncthreads();
    sb[t] += add;
    __syncthreads();
  }
  int base = sb[b] - bsum[b];  // exclusive prefix of block b (uniform)
  int n = b * 256 + t;
  int dv = (n < N) ? deg[n] : 0;
  sd[t] = dv;
  __syncthreads();
  for (int off = 1; off < 256; off <<= 1) {
    int add = (t >= off) ? sd[t - off] : 0;
    __syncthreads();
    sd[t] += add;
    __syncthreads();
  }
  if (n < N) rstart[n] = base + sd[t] - dv;
}

// ---------------- scatter (atomic slot reservation) + layer-1 GEMM fused ----------------
// Edge order within a node is nondeterministic — softmax+sum is order-agnostic.
__global__ __launch_bounds__(256, 3) void k_scatter_gemm(
    const int* __restrict__ src, const int* __restrict__ dst,
    const int* __restrict__ rstart, int* __restrict__ cur,
    int* __restrict__ ssrc, int E, int nblk,
    const float* __restrict__ A, const unsigned short* __restrict__ Wt,
    const float* __restrict__ a_src, const float* __restrict__ a_dst,
    unsigned short* __restrict__ xph, float* __restrict__ als,
    float* __restrict__ ald, int nrows) {
  if ((int)blockIdx.x >= nblk) {
    gemm_body<false>(A, Wt, a_src, a_dst, xph, als, ald, nrows, blockIdx.x - nblk);
    return;
  }
  int t0 = blockIdx.x * TILE;
  int end = t0 + TILE < E ? t0 + TILE : E;
  for (int i = t0 + threadIdx.x; i < end; i += 256) {
    int d = dst[i];
    int pos = rstart[d] + atomicAdd(&cur[d], 1);
    ssrc[pos] = src[i];
  }
}

// ---------------- layer-2 GEMM (standalone, f16 A) ----------------
__global__ __launch_bounds__(256, 3) void k_gemm2(
    const unsigned short* __restrict__ A, const unsigned short* __restrict__ Wt,
    const float* __restrict__ a_src, const float* __restrict__ a_dst,
    unsigned short* __restrict__ xph, float* __restrict__ als,
    float* __restrict__ ald, int nrows) {
  gemm_body<true>(A, Wt, a_src, a_dst, xph, als, ald, nrows, blockIdx.x);
}

// ---------------- per-node softmax + aggregation (one wave per node) ----------------
// HOUT: write f16 rows (layer-1 hbuf) vs f32 rows (final out).
// Fast path (d<=64): register-only; gathers overlapped; wave-uniform tail so
// every __shfl source lane stays live (round-3 lesson). No max-subtraction:
// logits bounded (~10), exp cannot overflow f32.
template <bool HOUT>
__global__ __launch_bounds__(256) void k_aggregate(
    const unsigned short* __restrict__ xph, const float* __restrict__ als,
    const float* __restrict__ ald, const int* __restrict__ rstart,
    const int* __restrict__ deg, const int* __restrict__ ssrc,
    const float* __restrict__ bias, void* __restrict__ outv, int N) {
  __shared__ float pbuf[4][128 * 4];  // slow-path only
  __shared__ int snbuf[4][128];       // slow-path only
  int wv = threadIdx.x >> 6;
  int lane = threadIdx.x & 63;
  int n = (blockIdx.x * blockDim.x + threadIdx.x) >> 6;
  if (n >= N) return;
  int start = rstart[n];
  int d = deg[n];
  float4 adv = *(const float4*)(ald + (size_t)n * 4);

  int cg = lane & 15;   // channel group: channels cg*8 .. cg*8+7
  int es = lane >> 4;   // edge slot 0..3
  int c0 = cg * 8;
  int h = cg >> 2;      // head of my channels
  float a[8] = {0.f, 0.f, 0.f, 0.f, 0.f, 0.f, 0.f, 0.f};
  float s0 = 0.f, s1 = 0.f, s2 = 0.f, s3 = 0.f;
  const uint4* xp4 = (const uint4*)xph;

  if (d <= 64) {
    bool valid = lane < d;
    int sn = ssrc[start + (valid ? lane : 0)];  // d>=1 (self-loop)
    float4 av = *(const float4*)(als + (size_t)sn * 4);
    int sA = __shfl(sn, es);
    int sB = __shfl(sn, es + 4);
    int sC = __shfl(sn, es + 8);
    int sD = __shfl(sn, es + 12);
    uint4 r0 = xp4[(size_t)sA * 16 + cg];
    uint4 r1 = xp4[(size_t)sB * 16 + cg];
    uint4 r2 = xp4[(size_t)sC * 16 + cg];
    uint4 r3 = xp4[(size_t)sD * 16 + cg];
    float p0 = valid ? __expf(leaky(av.x + adv.x)) : 0.f;
    float p1 = valid ? __expf(leaky(av.y + adv.y)) : 0.f;
    float p2 = valid ? __expf(leaky(av.z + adv.z)) : 0.f;
    float p3 = valid ? __expf(leaky(av.w + adv.w)) : 0.f;
    acc8h(a, getp(p0, p1, p2, p3, h, es), r0);
    if (d > 4)  acc8h(a, getp(p0, p1, p2, p3, h, es + 4), r1);
    if (d > 8)  acc8h(a, getp(p0, p1, p2, p3, h, es + 8), r2);
    if (d > 12) acc8h(a, getp(p0, p1, p2, p3, h, es + 12), r3);
    // wave-uniform tail: all 64 lanes active at every __shfl
    for (int tb = 16; tb < d; tb += 4) {
      int t = tb + es;
      int st = __shfl(sn, t);
      uint4 rv = xp4[(size_t)st * 16 + cg];
      acc8h(a, getp(p0, p1, p2, p3, h, t), rv);
    }
    s0 = wsum64(p0); s1 = wsum64(p1); s2 = wsum64(p2); s3 = wsum64(p3);
  } else {
    // ---- slow path (d>64): LDS-staged two-phase ----
    for (int base = 0; base < d; base += 64) {
      int i = base + lane;
      bool valid = i < d;
      int sn = valid ? ssrc[start + i] : 0;
      if (valid) snbuf[wv][i] = sn;
      float4 av = *(const float4*)(als + (size_t)sn * 4);
      float p0 = valid ? __expf(leaky(av.x + adv.x)) : 0.f;
      float p1 = valid ? __expf(leaky(av.y + adv.y)) : 0.f;
      float p2 = valid ? __expf(leaky(av.z + adv.z)) : 0.f;
      float p3 = valid ? __expf(leaky(av.w + adv.w)) : 0.f;
      if (valid) *(float4*)&pbuf[wv][i * 4] = make_float4(p0, p1, p2, p3);
      s0 += wsum64(p0); s1 += wsum64(p1); s2 += wsum64(p2); s3 += wsum64(p3);
    }
#pragma unroll 4
    for (int t = es; t < d; t += 4) {
      int sn = snbuf[wv][t];
      float p = pbuf[wv][t * 4 + h];
      uint4 rv = xp4[(size_t)sn * 16 + cg];
      acc8h(a, p, rv);
    }
  }

#pragma unroll
  for (int off = 16; off <= 32; off <<= 1) {
#pragma unroll
    for (int j = 0; j < 8; ++j) a[j] += __shfl_xor(a[j], off);
  }
  if (es == 0) {
    float sden = h == 0 ? s0 : h == 1 ? s1 : h == 2 ? s2 : s3;
    float inv = 1.f / (sden + 1e-16f);
    float4 bv0 = *(const float4*)(bias + c0);
    float4 bv1 = *(const float4*)(bias + c0 + 4);
    float o[8];
    o[0] = fmaxf(a[0] * inv + bv0.x, 0.f);
    o[1] = fmaxf(a[1] * inv + bv0.y, 0.f);
    o[2] = fmaxf(a[2] * inv + bv0.z, 0.f);
    o[3] = fmaxf(a[3] * inv + bv0.w, 0.f);
    o[4] = fmaxf(a[4] * inv + bv1.x, 0.f);
    o[5] = fmaxf(a[5] * inv + bv1.y, 0.f);
    o[6] = fmaxf(a[6] * inv + bv1.z, 0.f);
    o[7] = fmaxf(a[7] * inv + bv1.w, 0.f);
    if constexpr (HOUT) {
      union { uint4 v; _Float16 hh[8]; } u;
#pragma unroll
      for (int j = 0; j < 8; ++j) u.hh[j] = (_Float16)o[j];
      *(uint4*)((unsigned short*)outv + (size_t)n * 128 + c0) = u.v;
    } else {
      float* out = (float*)outv;
      *(float4*)(out + (size_t)n * 128 + c0) = make_float4(o[0], o[1], o[2], o[3]);
      *(float4*)(out + (size_t)n * 128 + c0 + 4) = make_float4(o[4], o[5], o[6], o[7]);
    }
  }
}

extern "C" void kernel_launch(void* const* d_in, const int* in_sizes, int n_in,
                              void* d_out, int out_size, void* d_ws, size_t ws_size,
                              hipStream_t stream) {
  const float* x   = (const float*)d_in[0];
  const int*   src = (const int*)d_in[1];
  const int*   dst = (const int*)d_in[2];
  const float* W0  = (const float*)d_in[3];
  const float* as0 = (const float*)d_in[4];
  const float* ad0 = (const float*)d_in[5];
  const float* b0  = (const float*)d_in[6];
  const float* W1  = (const float*)d_in[7];
  const float* as1 = (const float*)d_in[8];
  const float* ad1 = (const float*)d_in[9];
  const float* b1  = (const float*)d_in[10];
  float* out = (float*)d_out;

  int N = in_sizes[0] / 128;
  int E = in_sizes[1];
  int NBLK = (E + TILE - 1) / TILE;   // scatter blocks (104)
  int NBS = (N + 255) / 256;          // deg block-sum blocks (196, must be <=256)

  char* w = (char*)d_ws;
  auto alloc = [&](size_t bytes) {
    char* p = w;
    w += (bytes + 255) & ~(size_t)255;
    return p;
  };
  int* deg     = (int*)alloc((size_t)2 * N * 4);  // deg | cur contiguous (one zero pass)
  int* cur     = deg + N;
  int* rstart  = (int*)alloc((size_t)N * 4);
  int* bsum    = (int*)alloc((size_t)NBS * 4);
  int* ssrc    = (int*)alloc((size_t)E * 4);
  unsigned short* xph   = (unsigned short*)alloc((size_t)N * 128 * 2);
  unsigned short* hbufh = (unsigned short*)alloc((size_t)N * 128 * 2);
  float* als   = (float*)alloc((size_t)N * 4 * 4);
  float* ald   = (float*)alloc((size_t)N * 4 * 4);
  unsigned short* Wt0 = (unsigned short*)alloc(16384 * 2);
  unsigned short* Wt1 = (unsigned short*)alloc(16384 * 2);

  int gb = (N + 63) / 64;
  int NEBL = 1024;  // edge-hist blocks

  // k0: zero deg+cur
  k_zero<<<(2 * N + 255) / 256, 256, 0, stream>>>(deg, 2 * N);
  // k1: W f16 convert (blocks 0..127) + per-node degree hist (blocks 128..)
  k_hist_w<<<128 + NEBL, 256, 0, stream>>>(dst, deg, E, NEBL, W0, W1, Wt0, Wt1);
  // k2a: per-256-node sums;  k2b: rstart = exclusive scan of deg
  k_bsum<<<NBS, 256, 0, stream>>>(deg, bsum, N);
  k_rstart<<<NBS, 256, 0, stream>>>(deg, bsum, rstart, N, NBS);
  // k3: scatter (blocks 0..NBLK-1) + layer-1 GEMM (blocks NBLK..) — independent work
  k_scatter_gemm<<<NBLK + gb, 256, 0, stream>>>(
      src, dst, rstart, cur, ssrc, E, NBLK,
      x, Wt0, as0, ad0, xph, als, ald, N);
  // k5: layer-1 aggregate -> f16 hbuf
  k_aggregate<true><<<(N + 3) / 4, 256, 0, stream>>>(
      xph, als, ald, rstart, deg, ssrc, b0, hbufh, N);
  // k6: layer-2 GEMM (f16 A, no residual)
  k_gemm2<<<gb, 256, 0, stream>>>(hbufh, Wt1, as1, ad1, xph, als, ald, N);
  // k7: layer-2 aggregate -> f32 out
  k_aggregate<false><<<(N + 3) / 4, 256, 0, stream>>>(
      xph, als, ald, rstart, deg, ssrc, b1, out, N);
}

// Round 6
// 230.697 us; speedup vs baseline: 1.2643x; 1.2643x over previous
//
#include <hip/hip_runtime.h>
#include <math.h>

#define NEG_SLOPE 0.2f
#define BCAP 4096    // bucket capacity for k_build LDS (mean 2176, 41 sigma headroom)
#define TILE 8192    // edges per block in hist/scatter passes

using half8 = __attribute__((ext_vector_type(8))) _Float16;
using f32x4 = __attribute__((ext_vector_type(4))) float;

__device__ __forceinline__ float leaky(float x) { return x > 0.f ? x : NEG_SLOPE * x; }

__device__ __forceinline__ float wsum64(float v) {
#pragma unroll
  for (int off = 32; off; off >>= 1) v += __shfl_xor(v, off);
  return v;
}

// fp32 -> fp16 (RNE) and back. GEMM1 uses f16 hi + f16 residual for A (f32
// input x); GEMM2's A (hbuf) is STORED f16 so hi = exact, residual = 0 and
// the lo-MFMAs are skipped entirely. W single f16: dropped residual term
// ~2.5e-4, an order below the f16 xph storage floor (0.0039).
__device__ __forceinline__ unsigned short f2h(float f) {
  union { _Float16 h; unsigned short u; } x;
  x.h = (_Float16)f;
  return x.u;
}
__device__ __forceinline__ float h2f(unsigned short u) {
  union { unsigned short u; _Float16 h; } x;
  x.u = u;
  return (float)x.h;
}

// 8-channel f16 gather-accumulate: fmaf(p, fpext(f16), acc) -> v_fma_mix_f32
__device__ __forceinline__ void acc8h(float* a, float p, uint4 rv) {
  union { uint4 v; _Float16 h[8]; } u;
  u.v = rv;
#pragma unroll
  for (int j = 0; j < 8; ++j) a[j] = fmaf(p, (float)u.h[j], a[j]);
}

// lane-t's p for head h (4 cross-lane pulls + select)
__device__ __forceinline__ float getp(float p0, float p1, float p2, float p3,
                                      int h, int t) {
  float b0 = __shfl(p0, t), b1 = __shfl(p1, t);
  float b2 = __shfl(p2, t), b3 = __shfl(p3, t);
  float lo = (h & 1) ? b1 : b0;
  float hi = (h & 1) ? b3 : b2;
  return (h & 2) ? hi : lo;
}

// ---------------- f16 MFMA GEMM + fused logits (device body) ----------------
// AHALF=false: A is f32, split into f16 hi + f16 residual (4 MFMAs/ct).
// AHALF=true:  A is f16 (exact), no residual (2 MFMAs/ct, no Al buffer).
#define PA 136  // Ah/Al row pitch (f16): +8 pad
#define PW 40   // Wh row pitch
template <bool AHALF>
__device__ void gemm_body(
    const void* __restrict__ Av, const unsigned short* __restrict__ Wt,
    const float* __restrict__ a_src, const float* __restrict__ a_dst,
    unsigned short* __restrict__ xph, float* __restrict__ als,
    float* __restrict__ ald, int nrows, int blk) {
  __shared__ unsigned short Ah[64 * PA];
  __shared__ unsigned short Al[AHALF ? 64 : 64 * PA];  // unused when AHALF
  __shared__ unsigned short Wh[128 * PW];
  int t = threadIdx.x;
  int row0 = blk * 64;

  if constexpr (!AHALF) {
    const float4* A4 = (const float4*)Av;
#pragma unroll
    for (int p = 0; p < 8; ++p) {
      int idx = t + p * 256;  // 2048 float4 = 64 rows x 32
      int row = idx >> 5, k4 = idx & 31;
      int gr = row0 + row;
      float4 v = make_float4(0.f, 0.f, 0.f, 0.f);
      if (gr < nrows) v = A4[(size_t)gr * 32 + k4];
      ushort4 hi, lo;
      hi.x = f2h(v.x); lo.x = f2h(v.x - h2f(hi.x));
      hi.y = f2h(v.y); lo.y = f2h(v.y - h2f(hi.y));
      hi.z = f2h(v.z); lo.z = f2h(v.z - h2f(hi.z));
      hi.w = f2h(v.w); lo.w = f2h(v.w - h2f(hi.w));
      *(ushort4*)&Ah[row * PA + k4 * 4] = hi;
      *(ushort4*)&Al[row * PA + k4 * 4] = lo;
    }
  } else {
    const uint4* A4 = (const uint4*)Av;  // 8 halves per uint4; 16 per row
#pragma unroll
    for (int p = 0; p < 4; ++p) {
      int idx = t + p * 256;  // 1024 uint4 = 64 rows x 16
      int row = idx >> 4, k8 = idx & 15;
      int gr = row0 + row;
      uint4 v = make_uint4(0u, 0u, 0u, 0u);
      if (gr < nrows) v = A4[(size_t)gr * 16 + k8];
      *(uint4*)&Ah[row * PA + k8 * 8] = v;
    }
  }

  int lane = t & 63, wv = t >> 6;
  int wr = wv >> 1, wc = wv & 1;
  int ml = lane & 15, q = lane >> 4;
  f32x4 acc[2][4] = {};

  for (int kb = 0; kb < 4; ++kb) {
    __syncthreads();
    int k0 = kb * 32;
#pragma unroll
    for (int p = 0; p < 8; ++p) {
      int idx = t + p * 256;  // 2048 u32 = 128 n x 16 k-pairs
      int n = idx >> 4, kp = idx & 15;
      *(unsigned*)&Wh[n * PW + kp * 2] =
          *(const unsigned*)(Wt + (size_t)n * 128 + k0 + kp * 2);
    }
    __syncthreads();
    int kf = k0 + q * 8;
    half8 a_h0 = *(const half8*)&Ah[(wr * 32 + ml) * PA + kf];
    half8 a_h1 = *(const half8*)&Ah[(wr * 32 + 16 + ml) * PA + kf];
    half8 a_l0, a_l1;
    if constexpr (!AHALF) {
      a_l0 = *(const half8*)&Al[(wr * 32 + ml) * PA + kf];
      a_l1 = *(const half8*)&Al[(wr * 32 + 16 + ml) * PA + kf];
    }
#pragma unroll
    for (int ct = 0; ct < 4; ++ct) {
      int nb = (wc * 64 + ct * 16 + ml) * PW + q * 8;
      half8 b = *(const half8*)&Wh[nb];
      acc[0][ct] = __builtin_amdgcn_mfma_f32_16x16x32_f16(a_h0, b, acc[0][ct], 0, 0, 0);
      if constexpr (!AHALF)
        acc[0][ct] = __builtin_amdgcn_mfma_f32_16x16x32_f16(a_l0, b, acc[0][ct], 0, 0, 0);
      acc[1][ct] = __builtin_amdgcn_mfma_f32_16x16x32_f16(a_h1, b, acc[1][ct], 0, 0, 0);
      if constexpr (!AHALF)
        acc[1][ct] = __builtin_amdgcn_mfma_f32_16x16x32_f16(a_l1, b, acc[1][ct], 0, 0, 0);
    }
  }

  float asr[4], adr[4];
#pragma unroll
  for (int ct = 0; ct < 4; ++ct) {
    int col = (wc * 2 + (ct >> 1)) * 32 + (ct & 1) * 16 + ml;
    asr[ct] = a_src[col];
    adr[ct] = a_dst[col];
  }

#pragma unroll
  for (int rt = 0; rt < 2; ++rt) {
#pragma unroll
    for (int r = 0; r < 4; ++r) {
      int gr = row0 + wr * 32 + rt * 16 + q * 4 + r;
      bool valid = gr < nrows;
      if (valid) {
#pragma unroll
        for (int ct = 0; ct < 4; ++ct) {
          int gc = wc * 64 + ct * 16 + ml;
          xph[(size_t)gr * 128 + gc] = f2h(acc[rt][ct][r]);
        }
      }
      float p0 = acc[rt][0][r] * asr[0] + acc[rt][1][r] * asr[1];
      float p1 = acc[rt][2][r] * asr[2] + acc[rt][3][r] * asr[3];
      float d0 = acc[rt][0][r] * adr[0] + acc[rt][1][r] * adr[1];
      float d1 = acc[rt][2][r] * adr[2] + acc[rt][3][r] * adr[3];
#pragma unroll
      for (int off = 1; off <= 8; off <<= 1) {
        p0 += __shfl_xor(p0, off); p1 += __shfl_xor(p1, off);
        d0 += __shfl_xor(d0, off); d1 += __shfl_xor(d1, off);
      }
      if (ml == 0 && valid) {
        als[(size_t)gr * 4 + wc * 2] = p0;
        als[(size_t)gr * 4 + wc * 2 + 1] = p1;
        ald[(size_t)gr * 4 + wc * 2] = d0;
        ald[(size_t)gr * 4 + wc * 2 + 1] = d1;
      }
    }
  }
}

// ---------------- CSR pass 1 + W f16 convert (fused, disjoint block ranges) ----------------
// Round-5 lesson: per-edge GLOBAL atomics + random 4B scatter writes cost
// ~50 us (cross-XCD atomic serialization + 16x write amplification). Keep
// the LDS-cursor bucket chain: all per-edge atomics stay block-local.
__global__ __launch_bounds__(256) void k_hist_wsplit(
    const int* __restrict__ dst, int* __restrict__ blkhist, int E, int nb, int nblk,
    const float* __restrict__ W0, const float* __restrict__ W1,
    unsigned short* __restrict__ Wt0, unsigned short* __restrict__ Wt1) {
  __shared__ int h[512];
  if (blockIdx.x < 128) {
    int i = blockIdx.x * 256 + threadIdx.x;  // 32768 total
    int j = i & 16383;
    int k = j >> 7, n = j & 127;
    const float* W = (i < 16384) ? W0 : W1;
    unsigned short hv = f2h(W[j]);
    if (i < 16384) Wt0[n * 128 + k] = hv;
    else Wt1[n * 128 + k] = hv;
    return;
  }
  int blk = blockIdx.x - 128;
  for (int i = threadIdx.x; i < nb; i += 256) h[i] = 0;
  __syncthreads();
  int t0 = blk * TILE;
  int end = t0 + TILE < E ? t0 + TILE : E;
  for (int i = t0 + threadIdx.x; i < end; i += 256) atomicAdd(&h[dst[i] >> 7], 1);
  __syncthreads();
  for (int i = threadIdx.x; i < nb; i += 256) blkhist[(size_t)i * nblk + blk] = h[i];
}

// ---------------- pass 2: per-bucket scan over blocks -> block offsets + totals ----------------
__global__ __launch_bounds__(256) void k_bofs(int* __restrict__ blkhist,
                                              int* __restrict__ btot, int nblk) {
  __shared__ int sd[256];
  int b = blockIdx.x, t = threadIdx.x;
  int v = (t < nblk) ? blkhist[(size_t)b * nblk + t] : 0;
  sd[t] = v;
  __syncthreads();
  for (int off = 1; off < 256; off <<= 1) {
    int add = (t >= off) ? sd[t - off] : 0;
    __syncthreads();
    sd[t] += add;
    __syncthreads();
  }
  if (t < nblk) blkhist[(size_t)b * nblk + t] = sd[t] - v;  // exclusive
  if (t == 255) btot[b] = sd[255];
}

// ---------------- pass 3 + layer-1 GEMM (fused, disjoint block ranges) ----------------
// Packed entry: (dst&127)<<16 | src  — requires N < 65536.
__global__ __launch_bounds__(256, 3) void k_scatter2_gemm(
    const int* __restrict__ src, const int* __restrict__ dst,
    const int* __restrict__ blkhist, const int* __restrict__ btot,
    int* __restrict__ bstore, int E, int nb, int nblk,
    const float* __restrict__ A, const unsigned short* __restrict__ Wt,
    const float* __restrict__ a_src, const float* __restrict__ a_dst,
    unsigned short* __restrict__ xph, float* __restrict__ als,
    float* __restrict__ ald, int nrows) {
  if ((int)blockIdx.x >= nblk) {
    gemm_body<false>(A, Wt, a_src, a_dst, xph, als, ald, nrows, blockIdx.x - nblk);
    return;
  }
  __shared__ int sd[256];
  __shared__ int bb[512];
  __shared__ int cur[512];
  int t = threadIdx.x, blk = blockIdx.x;
  int v0 = (2 * t < nb) ? btot[2 * t] : 0;
  int v1 = (2 * t + 1 < nb) ? btot[2 * t + 1] : 0;
  int s = v0 + v1;
  sd[t] = s;
  __syncthreads();
  for (int off = 1; off < 256; off <<= 1) {
    int add = (t >= off) ? sd[t - off] : 0;
    __syncthreads();
    sd[t] += add;
    __syncthreads();
  }
  int run = sd[t] - s;
  if (2 * t < nb) bb[2 * t] = run;
  if (2 * t + 1 < nb) bb[2 * t + 1] = run + v0;
  __syncthreads();
  for (int i = t; i < nb; i += 256)
    cur[i] = bb[i] + blkhist[(size_t)i * nblk + blk];
  __syncthreads();
  int t0 = blk * TILE;
  int end = t0 + TILE < E ? t0 + TILE : E;
  for (int i = t0 + t; i < end; i += 256) {
    int d = dst[i];
    int pos = atomicAdd(&cur[d >> 7], 1);  // LDS atomic, block-local
    bstore[pos] = ((d & 127) << 16) | src[i];
  }
}

// ---------------- pass 4: per-bucket local CSR (one block per 128-node bucket) ----------------
__global__ __launch_bounds__(256) void k_build(
    const int* __restrict__ bstore, const int* __restrict__ btot,
    int* __restrict__ ssrc, int* __restrict__ deg, int* __restrict__ rstart, int N) {
  __shared__ int ls[BCAP];
  __shared__ unsigned char lloc[BCAP];
  __shared__ int lout[BCAP];
  __shared__ int hist[128];
  __shared__ int sc[128];
  __shared__ int lcur[128];
  __shared__ int red[256];
  int b = blockIdx.x;
  int t = threadIdx.x;
  int pacc = 0;
  for (int j = t; j < b; j += 256) pacc += btot[j];
  red[t] = pacc;
  __syncthreads();
  for (int off = 128; off; off >>= 1) {
    if (t < off) red[t] += red[t + off];
    __syncthreads();
  }
  int base = red[0];
  int cnt = btot[b];
  if (cnt > BCAP) cnt = BCAP;
  int nlo = b << 7;
  if (t < 128) { hist[t] = 0; lcur[t] = 0; }
  __syncthreads();
  for (int i = t; i < cnt; i += 256) {
    int e = bstore[base + i];
    int loc = e >> 16;
    ls[i] = e & 0xffff;
    lloc[i] = (unsigned char)loc;
    atomicAdd(&hist[loc], 1);
  }
  __syncthreads();
  int hv = (t < 128) ? hist[t] : 0;
  if (t < 128) sc[t] = hv;
  __syncthreads();
  for (int off = 1; off < 128; off <<= 1) {
    int add = (t < 128 && t >= off) ? sc[t - off] : 0;
    __syncthreads();
    if (t < 128) sc[t] += add;
    __syncthreads();
  }
  int lstart = (t < 128) ? sc[t] - hv : 0;  // exclusive
  if (t < 128) sc[t] = lstart;
  if (t < 128 && nlo + t < N) {
    deg[nlo + t] = hv;
    rstart[nlo + t] = base + lstart;
  }
  __syncthreads();
  for (int i = t; i < cnt; i += 256) {
    int loc = lloc[i];
    int slot = sc[loc] + atomicAdd(&lcur[loc], 1);
    lout[slot] = ls[i];
  }
  __syncthreads();
  for (int i = t; i < cnt; i += 256) ssrc[base + i] = lout[i];
}

// ---------------- layer-2 GEMM (standalone, f16 A, no residual) ----------------
__global__ __launch_bounds__(256, 3) void k_gemm2(
    const unsigned short* __restrict__ A, const unsigned short* __restrict__ Wt,
    const float* __restrict__ a_src, const float* __restrict__ a_dst,
    unsigned short* __restrict__ xph, float* __restrict__ als,
    float* __restrict__ ald, int nrows) {
  gemm_body<true>(A, Wt, a_src, a_dst, xph, als, ald, nrows, blockIdx.x);
}

// ---------------- per-node softmax + aggregation (one wave per node) ----------------
// HOUT: write f16 rows (layer-1 hbuf) vs f32 rows (final out).
// Fast path (d<=64): register-only; gathers overlapped; wave-uniform tail so
// every __shfl source lane stays live (round-3 lesson). No max-subtraction:
// logits bounded (~10), exp cannot overflow f32.
template <bool HOUT>
__global__ __launch_bounds__(256) void k_aggregate(
    const unsigned short* __restrict__ xph, const float* __restrict__ als,
    const float* __restrict__ ald, const int* __restrict__ rstart,
    const int* __restrict__ deg, const int* __restrict__ ssrc,
    const float* __restrict__ bias, void* __restrict__ outv, int N) {
  __shared__ float pbuf[4][128 * 4];  // slow-path only
  __shared__ int snbuf[4][128];       // slow-path only
  int wv = threadIdx.x >> 6;
  int lane = threadIdx.x & 63;
  int n = (blockIdx.x * blockDim.x + threadIdx.x) >> 6;
  if (n >= N) return;
  int start = rstart[n];
  int d = deg[n];
  float4 adv = *(const float4*)(ald + (size_t)n * 4);

  int cg = lane & 15;   // channel group: channels cg*8 .. cg*8+7
  int es = lane >> 4;   // edge slot 0..3
  int c0 = cg * 8;
  int h = cg >> 2;      // head of my channels
  float a[8] = {0.f, 0.f, 0.f, 0.f, 0.f, 0.f, 0.f, 0.f};
  float s0 = 0.f, s1 = 0.f, s2 = 0.f, s3 = 0.f;
  const uint4* xp4 = (const uint4*)xph;

  if (d <= 64) {
    bool valid = lane < d;
    int sn = ssrc[start + (valid ? lane : 0)];  // d>=1 (self-loop)
    float4 av = *(const float4*)(als + (size_t)sn * 4);
    int sA = __shfl(sn, es);
    int sB = __shfl(sn, es + 4);
    int sC = __shfl(sn, es + 8);
    int sD = __shfl(sn, es + 12);
    uint4 r0 = xp4[(size_t)sA * 16 + cg];
    uint4 r1 = xp4[(size_t)sB * 16 + cg];
    uint4 r2 = xp4[(size_t)sC * 16 + cg];
    uint4 r3 = xp4[(size_t)sD * 16 + cg];
    float p0 = valid ? __expf(leaky(av.x + adv.x)) : 0.f;
    float p1 = valid ? __expf(leaky(av.y + adv.y)) : 0.f;
    float p2 = valid ? __expf(leaky(av.z + adv.z)) : 0.f;
    float p3 = valid ? __expf(leaky(av.w + adv.w)) : 0.f;
    acc8h(a, getp(p0, p1, p2, p3, h, es), r0);
    if (d > 4)  acc8h(a, getp(p0, p1, p2, p3, h, es + 4), r1);
    if (d > 8)  acc8h(a, getp(p0, p1, p2, p3, h, es + 8), r2);
    if (d > 12) acc8h(a, getp(p0, p1, p2, p3, h, es + 12), r3);
    // wave-uniform tail: all 64 lanes active at every __shfl
    for (int tb = 16; tb < d; tb += 4) {
      int t = tb + es;
      int st = __shfl(sn, t);
      uint4 rv = xp4[(size_t)st * 16 + cg];
      acc8h(a, getp(p0, p1, p2, p3, h, t), rv);
    }
    s0 = wsum64(p0); s1 = wsum64(p1); s2 = wsum64(p2); s3 = wsum64(p3);
  } else {
    // ---- slow path (d>64): LDS-staged two-phase ----
    for (int base = 0; base < d; base += 64) {
      int i = base + lane;
      bool valid = i < d;
      int sn = valid ? ssrc[start + i] : 0;
      if (valid) snbuf[wv][i] = sn;
      float4 av = *(const float4*)(als + (size_t)sn * 4);
      float p0 = valid ? __expf(leaky(av.x + adv.x)) : 0.f;
      float p1 = valid ? __expf(leaky(av.y + adv.y)) : 0.f;
      float p2 = valid ? __expf(leaky(av.z + adv.z)) : 0.f;
      float p3 = valid ? __expf(leaky(av.w + adv.w)) : 0.f;
      if (valid) *(float4*)&pbuf[wv][i * 4] = make_float4(p0, p1, p2, p3);
      s0 += wsum64(p0); s1 += wsum64(p1); s2 += wsum64(p2); s3 += wsum64(p3);
    }
#pragma unroll 4
    for (int t = es; t < d; t += 4) {
      int sn = snbuf[wv][t];
      float p = pbuf[wv][t * 4 + h];
      uint4 rv = xp4[(size_t)sn * 16 + cg];
      acc8h(a, p, rv);
    }
  }

#pragma unroll
  for (int off = 16; off <= 32; off <<= 1) {
#pragma unroll
    for (int j = 0; j < 8; ++j) a[j] += __shfl_xor(a[j], off);
  }
  if (es == 0) {
    float sden = h == 0 ? s0 : h == 1 ? s1 : h == 2 ? s2 : s3;
    float inv = 1.f / (sden + 1e-16f);
    float4 bv0 = *(const float4*)(bias + c0);
    float4 bv1 = *(const float4*)(bias + c0 + 4);
    float o[8];
    o[0] = fmaxf(a[0] * inv + bv0.x, 0.f);
    o[1] = fmaxf(a[1] * inv + bv0.y, 0.f);
    o[2] = fmaxf(a[2] * inv + bv0.z, 0.f);
    o[3] = fmaxf(a[3] * inv + bv0.w, 0.f);
    o[4] = fmaxf(a[4] * inv + bv1.x, 0.f);
    o[5] = fmaxf(a[5] * inv + bv1.y, 0.f);
    o[6] = fmaxf(a[6] * inv + bv1.z, 0.f);
    o[7] = fmaxf(a[7] * inv + bv1.w, 0.f);
    if constexpr (HOUT) {
      union { uint4 v; _Float16 hh[8]; } u;
#pragma unroll
      for (int j = 0; j < 8; ++j) u.hh[j] = (_Float16)o[j];
      *(uint4*)((unsigned short*)outv + (size_t)n * 128 + c0) = u.v;
    } else {
      float* out = (float*)outv;
      *(float4*)(out + (size_t)n * 128 + c0) = make_float4(o[0], o[1], o[2], o[3]);
      *(float4*)(out + (size_t)n * 128 + c0 + 4) = make_float4(o[4], o[5], o[6], o[7]);
    }
  }
}

extern "C" void kernel_launch(void* const* d_in, const int* in_sizes, int n_in,
                              void* d_out, int out_size, void* d_ws, size_t ws_size,
                              hipStream_t stream) {
  const float* x   = (const float*)d_in[0];
  const int*   src = (const int*)d_in[1];
  const int*   dst = (const int*)d_in[2];
  const float* W0  = (const float*)d_in[3];
  const float* as0 = (const float*)d_in[4];
  const float* ad0 = (const float*)d_in[5];
  const float* b0  = (const float*)d_in[6];
  const float* W1  = (const float*)d_in[7];
  const float* as1 = (const float*)d_in[8];
  const float* ad1 = (const float*)d_in[9];
  const float* b1  = (const float*)d_in[10];
  float* out = (float*)d_out;

  int N = in_sizes[0] / 128;
  int E = in_sizes[1];
  int NB = (N + 127) >> 7;          // buckets of 128 nodes (391)
  int NBLK = (E + TILE - 1) / TILE; // hist/scatter blocks (104, must be <=256)

  char* w = (char*)d_ws;
  auto alloc = [&](size_t bytes) {
    char* p = w;
    w += (bytes + 255) & ~(size_t)255;
    return p;
  };
  int* deg     = (int*)alloc((size_t)N * 4);
  int* rstart  = (int*)alloc((size_t)N * 4);
  int* blkhist = (int*)alloc((size_t)NB * NBLK * 4);
  int* btot    = (int*)alloc((size_t)NB * 4);
  int* bstore  = (int*)alloc((size_t)E * 4);
  int* ssrc    = (int*)alloc((size_t)E * 4);
  unsigned short* xph   = (unsigned short*)alloc((size_t)N * 128 * 2);
  unsigned short* hbufh = (unsigned short*)alloc((size_t)N * 128 * 2);
  float* als   = (float*)alloc((size_t)N * 4 * 4);
  float* ald   = (float*)alloc((size_t)N * 4 * 4);
  unsigned short* Wt0 = (unsigned short*)alloc(16384 * 2);
  unsigned short* Wt1 = (unsigned short*)alloc(16384 * 2);

  int gb = (N + 63) / 64;

  // k1: W f16 convert (blocks 0..127) + per-block dst histograms (blocks 128..)
  k_hist_wsplit<<<128 + NBLK, 256, 0, stream>>>(dst, blkhist, E, NB, NBLK,
                                                W0, W1, Wt0, Wt1);
  // k2: per-bucket exclusive scan over blocks
  k_bofs<<<NB, 256, 0, stream>>>(blkhist, btot, NBLK);
  // k3: scatter (blocks 0..NBLK-1) + layer-1 GEMM (blocks NBLK..) — independent work
  k_scatter2_gemm<<<NBLK + gb, 256, 0, stream>>>(
      src, dst, blkhist, btot, bstore, E, NB, NBLK,
      x, Wt0, as0, ad0, xph, als, ald, N);
  // k4: per-bucket local CSR
  k_build<<<NB, 256, 0, stream>>>(bstore, btot, ssrc, deg, rstart, N);
  // k5: layer-1 aggregate -> f16 hbuf
  k_aggregate<true><<<(N + 3) / 4, 256, 0, stream>>>(
      xph, als, ald, rstart, deg, ssrc, b0, hbufh, N);
  // k6: layer-2 GEMM (f16 A, no residual)
  k_gemm2<<<gb, 256, 0, stream>>>(hbufh, Wt1, as1, ad1, xph, als, ald, N);
  // k7: layer-2 aggregate -> f32 out
  k_aggregate<false><<<(N + 3) / 4, 256, 0, stream>>>(
      xph, als, ald, rstart, deg, ssrc, b1, out, N);
}